// Round 9
// baseline (287.533 us; speedup 1.0000x reference)
//
#include <hip/hip_runtime.h>
#include <hip/hip_bf16.h>
#include <math.h>

// GAT x3 + LayerNorm for MI355X (gfx950).
// R9: layer-0 restructured as aggregate-then-project (aggregation of raw
// 16-wide f32 x rows, L2-resident; per-node 16->256 projection in-register
// with bias+ELU fused). K1 mega-dispatch = Wf1/Wf2/wedot prep + layer-0 dots
// (va0 built in-block) + degree histogram. 9 dispatches + 1 memset.
// Carried: bf16 h, al = A @ va via extra MFMA col-tile, inline exp weights,
// int2 edge records, 2-stream agg4 / 4-stream agg_ln wide-load gathers.

typedef __attribute__((ext_vector_type(8))) short short8;
typedef __attribute__((ext_vector_type(4))) float float4v;

__device__ __forceinline__ float wave_sum(float v) {
#pragma unroll
  for (int off = 32; off > 0; off >>= 1) v += __shfl_xor(v, off, 64);
  return v;
}

__device__ __forceinline__ unsigned short f2bf(float v) {
  unsigned u = __float_as_uint(v);
  unsigned r = u + 0x7fff + ((u >> 16) & 1);  // RNE
  return (unsigned short)(r >> 16);
}

__device__ __forceinline__ float bf2f(unsigned short u) {
  return __uint_as_float(((unsigned)u) << 16);
}

// leaky_relu(0.2) + clamp + exp (softmax max cancels in the ratio)
__device__ __forceinline__ float edge_w(float a) {
  a = fmaxf(a, 0.2f * a);
  a = fminf(a, 30.f);
  return __expf(a);
}

// ---------------- K1 mega-dispatch ----------------
// blocks [0,272): Wf1 (16 W1-tiles + 1 va1 tile, bf16 fragment order)
// blocks [272,352): Wf2 (4 W2-tiles + 1 va2 tile)
// block 352: wedot[0..8]
// blocks [353, 353+gD): layer-0 dots (va0 built per block in LDS)
// blocks [353+gD, ...): degree histogram + edge_attr sums
__global__ __launch_bounds__(256) void k1_kernel(
    const float* __restrict__ x, const int* __restrict__ dstv, const float* __restrict__ eattr,
    const float* __restrict__ W0, const float* __restrict__ as0, const float* __restrict__ ad0,
    const float* __restrict__ We0, const float* __restrict__ ae0,
    const float* __restrict__ W1, const float* __restrict__ as1, const float* __restrict__ ad1,
    const float* __restrict__ We1, const float* __restrict__ ae1,
    const float* __restrict__ W2, const float* __restrict__ as2, const float* __restrict__ ad2,
    const float* __restrict__ We2, const float* __restrict__ ae2,
    unsigned short* __restrict__ Wf1, unsigned short* __restrict__ Wf2,
    float* __restrict__ wedot, float* __restrict__ al_s, float* __restrict__ al_d,
    int* __restrict__ deg, float* __restrict__ asum, int N, int E, int gD) {
  int b = blockIdx.x;
  int tid = threadIdx.x;
  if (b < 272) {  // Wf1
    int idx = b * 256 + tid;
    int j = idx & 7, lane = (idx >> 3) & 63, ks = (idx >> 9) & 7, nt = idx >> 12;
    int k = ks * 32 + (lane >> 4) * 8 + j;
    int col = lane & 15;
    float v = 0.f;
    if (nt < 16) {
      v = W1[(size_t)k * 256 + nt * 16 + col];
    } else if (col < 4) {
      for (int c = 0; c < 64; c++) v = fmaf(W1[(size_t)k * 256 + col * 64 + c], as1[col * 64 + c], v);
    } else if (col < 8) {
      int h = col - 4;
      for (int c = 0; c < 64; c++) v = fmaf(W1[(size_t)k * 256 + h * 64 + c], ad1[h * 64 + c], v);
    }
    Wf1[idx] = f2bf(v);
  } else if (b < 352) {  // Wf2
    int idx = (b - 272) * 256 + tid;
    int j = idx & 7, lane = (idx >> 3) & 63, ks = (idx >> 9) & 7, nt = idx >> 12;
    int k = ks * 32 + (lane >> 4) * 8 + j;
    int col = lane & 15;
    float v = 0.f;
    if (nt < 4) {
      v = W2[(size_t)k * 64 + nt * 16 + col];
    } else if (col < 1) {
      for (int c = 0; c < 64; c++) v = fmaf(W2[(size_t)k * 64 + c], as2[c], v);
    } else if (col < 2) {
      for (int c = 0; c < 64; c++) v = fmaf(W2[(size_t)k * 64 + c], ad2[c], v);
    }
    Wf2[idx] = f2bf(v);
  } else if (b == 352) {  // wedot
    if (tid >= 64) return;
    int c = tid;
    for (int h = 0; h < 4; h++) {
      float v = wave_sum(We0[h * 64 + c] * ae0[h * 64 + c]);
      if (c == 0) wedot[h] = v;
    }
    for (int h = 0; h < 4; h++) {
      float v = wave_sum(We1[h * 64 + c] * ae1[h * 64 + c]);
      if (c == 0) wedot[4 + h] = v;
    }
    float v = wave_sum(We2[c] * ae2[c]);
    if (c == 0) wedot[8] = v;
  } else if (b < 353 + gD) {  // layer-0 dots: al = x @ va0
    __shared__ float va[128];  // [k*8 + col], col<4: as, col in [4,8): ad
    if (tid < 128) {
      int k = tid >> 3, col = tid & 7;
      float v = 0.f;
      if (col < 4) {
        for (int c = 0; c < 64; c++) v = fmaf(W0[(size_t)k * 256 + col * 64 + c], as0[col * 64 + c], v);
      } else {
        int h = col - 4;
        for (int c = 0; c < 64; c++) v = fmaf(W0[(size_t)k * 256 + h * 64 + c], ad0[h * 64 + c], v);
      }
      va[tid] = v;
    }
    __syncthreads();
    int node = (b - 353) * 256 + tid;
    if (node >= N) return;
    const float4* xr = (const float4*)(x + (size_t)node * 16);
    float4 xv[4];
#pragma unroll
    for (int q = 0; q < 4; q++) xv[q] = xr[q];
    float al[8];
#pragma unroll
    for (int j = 0; j < 8; j++) al[j] = 0.f;
#pragma unroll
    for (int k = 0; k < 16; k++) {
      float xk = ((const float*)xv)[k];
#pragma unroll
      for (int j = 0; j < 8; j++) al[j] = fmaf(xk, va[k * 8 + j], al[j]);
    }
    ((float4*)al_s)[node] = make_float4(al[0], al[1], al[2], al[3]);
    ((float4*)al_d)[node] = make_float4(al[4], al[5], al[6], al[7]);
  } else {  // degree histogram
    int e = (b - 353 - gD) * 256 + tid;
    if (e >= E) return;
    int d = dstv[e];
    atomicAdd(&deg[d], 1);
    atomicAdd(&asum[d], eattr[e]);
  }
}

// Single-pass scan: thread t owns C contiguous nodes.
__global__ __launch_bounds__(1024) void scan_kernel(const int* __restrict__ deg,
                                                    int* __restrict__ row_ptr, int n) {
  int tid = threadIdx.x, wid = tid >> 6, lane = tid & 63;
  int C = (n + 1023) >> 10;
  int base = tid * C;
  int sum = 0;
  for (int j = 0; j < C; j++) {
    int i = base + j;
    if (i < n) sum += deg[i] + 1;
  }
  int sc = sum;
#pragma unroll
  for (int off = 1; off < 64; off <<= 1) {
    int t = __shfl_up(sc, off, 64);
    if (lane >= off) sc += t;
  }
  __shared__ int wtot[16], wexc[16];
  __shared__ int total;
  if (lane == 63) wtot[wid] = sc;
  __syncthreads();
  if (tid == 0) {
    int run = 0;
#pragma unroll
    for (int i = 0; i < 16; i++) { int t = wtot[i]; wexc[i] = run; run += t; }
    total = run;
  }
  __syncthreads();
  int run = wexc[wid] + (sc - sum);
  for (int j = 0; j < C; j++) {
    int i = base + j;
    if (i < n) {
      row_ptr[i] = run;
      run += deg[i] + 1;
    }
  }
  if (tid == 0) row_ptr[n] = total;
}

// Merged CSR fill: t<E scatters real edges; t>=E appends self loop.
__global__ void fill_kernel(const int* __restrict__ src, const int* __restrict__ dst,
                            const float* __restrict__ eattr, const int* __restrict__ row_ptr,
                            const int* __restrict__ deg, const float* __restrict__ asum,
                            int* __restrict__ fill, int2* __restrict__ edge, int E, int n) {
  int t = blockIdx.x * 256 + threadIdx.x;
  if (t < E) {
    int d = dst[t];
    int pos = row_ptr[d] + atomicAdd(&fill[d], 1);
    edge[pos] = make_int2(src[t], __float_as_int(eattr[t]));
  } else {
    int i = t - E;
    if (i < n) {
      int dg = deg[i];
      edge[row_ptr[i] + dg] = make_int2(i, __float_as_int(asum[i] / fmaxf((float)dg, 1.f)));
    }
  }
}

// Layer-0 fused aggregate-then-project: one wave per node.
// Lane = h*16 + c : accumulates Z[h][c] = sum_e w^h * x[src][c]  (f32, 64B
// rows, L2-resident). Epilogue: out[h*64 + c*4 + jj] = sum_cc Zn[h][cc] *
// W0[cc][col] with the W0 fragment (16 float4) held in registers and Zn
// redistributed by 16 shuffles. bias+ELU fused; bf16 out.
__global__ __launch_bounds__(256) void agg0_kernel(
    const int* __restrict__ row_ptr, const int2* __restrict__ edge,
    const float* __restrict__ al_s, const float* __restrict__ al_d,
    const float* __restrict__ wedot, const float* __restrict__ x,
    const float* __restrict__ W0, const float* __restrict__ bias,
    unsigned short* __restrict__ out, int n) {
  int node = blockIdx.x * 4 + (threadIdx.x >> 6);
  if (node >= n) return;
  int lane = threadIdx.x & 63;
  int h = lane >> 4, c = lane & 15;
  // W0 fragment: w0r[cc] = W0[cc][4*lane .. 4*lane+3]  (col0 = h*64+c*4 = 4*lane)
  float4 w0r[16];
#pragma unroll
  for (int cc = 0; cc < 16; cc++) w0r[cc] = ((const float4*)(W0 + (size_t)cc * 256))[lane];

  float wd = wedot[h];
  float adn = al_d[(size_t)node * 4 + h];
  int beg = row_ptr[node], end = row_ptr[node + 1];
  float Z = 0.f, den = 0.f;
  int e = beg;
  for (; e + 8 <= end; e += 8) {
    int2 g[8];
    float al[8], xv[8];
#pragma unroll
    for (int t = 0; t < 8; t++) g[t] = edge[e + t];
#pragma unroll
    for (int t = 0; t < 8; t++) al[t] = al_s[(size_t)g[t].x * 4 + h];
#pragma unroll
    for (int t = 0; t < 8; t++) xv[t] = x[(size_t)g[t].x * 16 + c];
#pragma unroll
    for (int t = 0; t < 8; t++) {
      float w = edge_w(al[t] + adn + __int_as_float(g[t].y) * wd);
      den += w;
      Z = fmaf(w, xv[t], Z);
    }
  }
  for (; e < end; e++) {
    int2 g = edge[e];
    float al = al_s[(size_t)g.x * 4 + h];
    float xv = x[(size_t)g.x * 16 + c];
    float w = edge_w(al + adn + __int_as_float(g.y) * wd);
    den += w;
    Z = fmaf(w, xv, Z);
  }
  float zn = Z / (den + 1e-16f);
  // redistribute Zn within the 16-lane head group
  float zc[16];
  int basel = lane & 48;  // h*16
#pragma unroll
  for (int cc = 0; cc < 16; cc++) zc[cc] = __shfl(zn, basel + cc, 64);
  float o[4];
  float4 b4 = ((const float4*)bias)[lane];
#pragma unroll
  for (int jj = 0; jj < 4; jj++) o[jj] = ((const float*)&b4)[jj];
#pragma unroll
  for (int cc = 0; cc < 16; cc++) {
#pragma unroll
    for (int jj = 0; jj < 4; jj++) o[jj] = fmaf(zc[cc], ((const float*)&w0r[cc])[jj], o[jj]);
  }
  ushort4 o4;
  float ox = o[0] > 0.f ? o[0] : expm1f(o[0]);
  float oy = o[1] > 0.f ? o[1] : expm1f(o[1]);
  float oz = o[2] > 0.f ? o[2] : expm1f(o[2]);
  float ow = o[3] > 0.f ? o[3] : expm1f(o[3]);
  o4.x = f2bf(ox);
  o4.y = f2bf(oy);
  o4.z = f2bf(oz);
  o4.w = f2bf(ow);
  ((ushort4*)out)[(size_t)node * 64 + lane] = o4;
}

// bf16 MFMA GEMM (K=256): bf16 out; al_s/al_d from the extra va col-tile.
template <int M, int H>
__global__ __launch_bounds__(64) void mfma_gemm_dots(
    const unsigned short* __restrict__ Abf, const unsigned short* __restrict__ Wfrag,
    unsigned short* __restrict__ out, float* __restrict__ al_s, float* __restrict__ al_d,
    int n) {
  int lane = threadIdx.x;
  int row0 = blockIdx.x * 16;
  int m = lane & 15, q = lane >> 4;

  short8 afrag[8];
  int r = row0 + m;
  if (r < n) {
    const short8* arow = (const short8*)(Abf + (size_t)r * 256);
#pragma unroll
    for (int ks = 0; ks < 8; ks++) afrag[ks] = arow[ks * 4 + q];
  } else {
#pragma unroll
    for (int ks = 0; ks < 8; ks++) afrag[ks] = (short8)0;
  }

  const short8* wf = (const short8*)Wfrag;

  auto epi = [&](int tile, float4v acc) {
    int col = tile * 16 + m;
#pragma unroll
    for (int reg = 0; reg < 4; reg++) {
      int rr = row0 + q * 4 + reg;
      if (rr < n) out[(size_t)rr * M + col] = f2bf(acc[reg]);
    }
  };

  for (int nt = 0; nt < M / 16; nt += 2) {
    const short8* b0 = wf + (size_t)nt * 8 * 64 + lane;
    const short8* b1 = b0 + 8 * 64;
    short8 bf0[8], bf1[8];
#pragma unroll
    for (int ks = 0; ks < 8; ks++) {
      bf0[ks] = b0[ks * 64];
      bf1[ks] = b1[ks * 64];
    }
    float4v acc0 = {0.f, 0.f, 0.f, 0.f};
    float4v acc1 = {0.f, 0.f, 0.f, 0.f};
#pragma unroll
    for (int ks = 0; ks < 8; ks++) {
      acc0 = __builtin_amdgcn_mfma_f32_16x16x32_bf16(afrag[ks], bf0[ks], acc0, 0, 0, 0);
      acc1 = __builtin_amdgcn_mfma_f32_16x16x32_bf16(afrag[ks], bf1[ks], acc1, 0, 0, 0);
    }
    epi(nt, acc0);
    epi(nt + 1, acc1);
  }

  // va tile -> al_s / al_d
  {
    const short8* bl = wf + (size_t)(M / 16) * 8 * 64 + lane;
    short8 bf[8];
#pragma unroll
    for (int ks = 0; ks < 8; ks++) bf[ks] = bl[ks * 64];
    float4v acc = {0.f, 0.f, 0.f, 0.f};
#pragma unroll
    for (int ks = 0; ks < 8; ks++)
      acc = __builtin_amdgcn_mfma_f32_16x16x32_bf16(afrag[ks], bf[ks], acc, 0, 0, 0);
#pragma unroll
    for (int reg = 0; reg < 4; reg++) {
      int rr = row0 + q * 4 + reg;
      if (rr < n) {
        if (m < H) al_s[(size_t)rr * H + m] = acc[reg];
        else if (m < 2 * H) al_d[(size_t)rr * H + (m - H)] = acc[reg];
      }
    }
  }
}

// H=4 aggregation: one wave per node, TWO edge streams (lanes 0-31 / 32-63);
// lane holds channels l*8..l*8+7 (one dwordx4 instr fetches two 512B rows).
__global__ __launch_bounds__(256) void agg4_kernel(
    const int* __restrict__ row_ptr, const int2* __restrict__ edge,
    const float* __restrict__ al_s, const float* __restrict__ al_d,
    const float* __restrict__ wedot, const unsigned short* __restrict__ B,
    const float* __restrict__ bias, unsigned short* __restrict__ out, int n) {
  int node = blockIdx.x * 4 + (threadIdx.x >> 6);
  if (node >= n) return;
  int lane = threadIdx.x & 63;
  int half = lane >> 5;
  int l = lane & 31;
  int h4 = l >> 3;
  float wd = wedot[h4];
  float adn = al_d[(size_t)node * 4 + h4];
  int beg = row_ptr[node], end = row_ptr[node + 1];
  int cnt = end - beg;
  int cntA = (cnt + 1) >> 1;
  int myCnt = half ? (cnt - cntA) : cntA;
  int myBeg = half ? (beg + cntA) : beg;

  float acc[8];
#pragma unroll
  for (int j = 0; j < 8; j++) acc[j] = 0.f;
  float den = 0.f;

  int i = 0;
  for (; i + 4 <= cntA; i += 4) {
    int2 g[4];
    float als[4];
    short8 bv[4];
    bool val[4];
#pragma unroll
    for (int t = 0; t < 4; t++) {
      val[t] = (i + t) < myCnt;
      int e = val[t] ? (myBeg + i + t) : (end - 1);
      g[t] = edge[e];
    }
#pragma unroll
    for (int t = 0; t < 4; t++) als[t] = al_s[(size_t)g[t].x * 4 + h4];
#pragma unroll
    for (int t = 0; t < 4; t++) bv[t] = ((const short8*)(B + (size_t)g[t].x * 256))[l];
#pragma unroll
    for (int t = 0; t < 4; t++) {
      float w = edge_w(als[t] + adn + __int_as_float(g[t].y) * wd);
      w = val[t] ? w : 0.f;
      den += w;
      const unsigned short* bp = (const unsigned short*)&bv[t];
#pragma unroll
      for (int j = 0; j < 8; j++) acc[j] = fmaf(w, bf2f(bp[j]), acc[j]);
    }
  }
  for (; i < cntA; i++) {
    bool valid = i < myCnt;
    int e = valid ? (myBeg + i) : (end - 1);
    int2 g = edge[e];
    float als = al_s[(size_t)g.x * 4 + h4];
    short8 bv = ((const short8*)(B + (size_t)g.x * 256))[l];
    float w = edge_w(als + adn + __int_as_float(g.y) * wd);
    w = valid ? w : 0.f;
    den += w;
    const unsigned short* bp = (const unsigned short*)&bv;
#pragma unroll
    for (int j = 0; j < 8; j++) acc[j] = fmaf(w, bf2f(bp[j]), acc[j]);
  }

  den += __shfl_xor(den, 32, 64);
#pragma unroll
  for (int j = 0; j < 8; j++) acc[j] += __shfl_xor(acc[j], 32, 64);

  if (half == 0) {
    float inv = 1.f / (den + 1e-16f);
    float4 b0 = ((const float4*)bias)[l * 2];
    float4 b1 = ((const float4*)bias)[l * 2 + 1];
    unsigned short o8[8];
#pragma unroll
    for (int j = 0; j < 8; j++) {
      float bjv = (j < 4) ? ((const float*)&b0)[j] : ((const float*)&b1)[j - 4];
      float o = acc[j] * inv + bjv;
      o = o > 0.f ? o : expm1f(o);
      o8[j] = f2bf(o);
    }
    ((short8*)(out + (size_t)node * 256))[l] = *(short8*)o8;
  }
}

// H=1 aggregation + bias + LayerNorm: one wave per node, FOUR edge streams.
__global__ __launch_bounds__(256) void agg_ln_kernel(
    const int* __restrict__ row_ptr, const int2* __restrict__ edge,
    const float* __restrict__ al_s, const float* __restrict__ al_d,
    const float* __restrict__ wedot, const unsigned short* __restrict__ B,
    const float* __restrict__ bias, const float* __restrict__ ln_g,
    const float* __restrict__ ln_b, float* __restrict__ out, int n) {
  int node = blockIdx.x * 4 + (threadIdx.x >> 6);
  if (node >= n) return;
  int lane = threadIdx.x & 63;
  int q = lane >> 4;
  int l = lane & 15;
  float wd = wedot[0];
  float adn = al_d[node];
  int beg = row_ptr[node], end = row_ptr[node + 1];
  int cnt = end - beg;
  int base = cnt >> 2, rem = cnt & 3;
  int myCnt = base + (q < rem ? 1 : 0);
  int myBeg = beg + q * base + min(q, rem);
  int iters = base + (rem ? 1 : 0);

  float4 acc = make_float4(0.f, 0.f, 0.f, 0.f);
  float den = 0.f;

  int i = 0;
  for (; i + 2 <= iters; i += 2) {
    int2 g[2];
    float als[2];
    ushort4 bv[2];
    bool val[2];
#pragma unroll
    for (int t = 0; t < 2; t++) {
      val[t] = (i + t) < myCnt;
      int e = val[t] ? (myBeg + i + t) : (end - 1);
      g[t] = edge[e];
    }
#pragma unroll
    for (int t = 0; t < 2; t++) als[t] = al_s[g[t].x];
#pragma unroll
    for (int t = 0; t < 2; t++) bv[t] = ((const ushort4*)(B + (size_t)g[t].x * 64))[l];
#pragma unroll
    for (int t = 0; t < 2; t++) {
      float w = edge_w(als[t] + adn + __int_as_float(g[t].y) * wd);
      w = val[t] ? w : 0.f;
      den += w;
      acc.x = fmaf(w, bf2f(bv[t].x), acc.x);
      acc.y = fmaf(w, bf2f(bv[t].y), acc.y);
      acc.z = fmaf(w, bf2f(bv[t].z), acc.z);
      acc.w = fmaf(w, bf2f(bv[t].w), acc.w);
    }
  }
  for (; i < iters; i++) {
    bool valid = i < myCnt;
    int e = valid ? (myBeg + i) : (end - 1);
    int2 g = edge[e];
    float als = al_s[g.x];
    ushort4 bv = ((const ushort4*)(B + (size_t)g.x * 64))[l];
    float w = edge_w(als + adn + __int_as_float(g.y) * wd);
    w = valid ? w : 0.f;
    den += w;
    acc.x = fmaf(w, bf2f(bv.x), acc.x);
    acc.y = fmaf(w, bf2f(bv.y), acc.y);
    acc.z = fmaf(w, bf2f(bv.z), acc.z);
    acc.w = fmaf(w, bf2f(bv.w), acc.w);
  }

  den += __shfl_xor(den, 32, 64);
  den += __shfl_xor(den, 16, 64);
  acc.x += __shfl_xor(acc.x, 32, 64);
  acc.y += __shfl_xor(acc.y, 32, 64);
  acc.z += __shfl_xor(acc.z, 32, 64);
  acc.w += __shfl_xor(acc.w, 32, 64);
  acc.x += __shfl_xor(acc.x, 16, 64);
  acc.y += __shfl_xor(acc.y, 16, 64);
  acc.z += __shfl_xor(acc.z, 16, 64);
  acc.w += __shfl_xor(acc.w, 16, 64);

  float inv = 1.f / (den + 1e-16f);
  float4 b4 = ((const float4*)bias)[l];
  float4 o;
  o.x = acc.x * inv + b4.x;
  o.y = acc.y * inv + b4.y;
  o.z = acc.z * inv + b4.z;
  o.w = acc.w * inv + b4.w;
  float s = (o.x + o.y) + (o.z + o.w);
#pragma unroll
  for (int off = 1; off < 16; off <<= 1) s += __shfl_xor(s, off, 64);
  float mu = s * (1.f / 64.f);
  float dx = o.x - mu, dy = o.y - mu, dz = o.z - mu, dw = o.w - mu;
  float v = (dx * dx + dy * dy) + (dz * dz + dw * dw);
#pragma unroll
  for (int off = 1; off < 16; off <<= 1) v += __shfl_xor(v, off, 64);
  float rs = rsqrtf(v * (1.f / 64.f) + 1e-5f);
  if (q == 0) {
    float4 g4 = ((const float4*)ln_g)[l];
    float4 lb4 = ((const float4*)ln_b)[l];
    float4 r;
    r.x = dx * rs * g4.x + lb4.x;
    r.y = dy * rs * g4.y + lb4.y;
    r.z = dz * rs * g4.z + lb4.z;
    r.w = dw * rs * g4.w + lb4.w;
    ((float4*)(out + (size_t)node * 64))[l] = r;
  }
}

extern "C" void kernel_launch(void* const* d_in, const int* in_sizes, int n_in,
                              void* d_out, int out_size, void* d_ws, size_t ws_size,
                              hipStream_t stream) {
  const float* x = (const float*)d_in[0];
  const int* ei = (const int*)d_in[1];
  const float* eattr = (const float*)d_in[2];
  const float* W0 = (const float*)d_in[3];
  const float* as0 = (const float*)d_in[4];
  const float* ad0 = (const float*)d_in[5];
  const float* We0 = (const float*)d_in[6];
  const float* ae0 = (const float*)d_in[7];
  const float* b0 = (const float*)d_in[8];
  const float* W1 = (const float*)d_in[9];
  const float* as1 = (const float*)d_in[10];
  const float* ad1 = (const float*)d_in[11];
  const float* We1 = (const float*)d_in[12];
  const float* ae1 = (const float*)d_in[13];
  const float* b1 = (const float*)d_in[14];
  const float* W2 = (const float*)d_in[15];
  const float* as2 = (const float*)d_in[16];
  const float* ad2 = (const float*)d_in[17];
  const float* We2 = (const float*)d_in[18];
  const float* ae2 = (const float*)d_in[19];
  const float* b2 = (const float*)d_in[20];
  const float* lng = (const float*)d_in[21];
  const float* lnb = (const float*)d_in[22];
  float* outp = (float*)d_out;

  const int N = in_sizes[0] / 16;
  const int E = in_sizes[1] / 2;
  const int P = E + N;
  const int* srcv = ei;
  const int* dstv = ei + E;

  char* w = (char*)d_ws;
  size_t off = 0;
  auto alloc = [&](size_t bytes) -> void* {
    void* p = w + off;
    off += (bytes + 255) & ~(size_t)255;
    return p;
  };
  int* deg = (int*)alloc((size_t)N * 4);
  float* asum = (float*)alloc((size_t)N * 4);
  int* fill = (int*)alloc((size_t)N * 4);
  size_t zero_bytes = off;
  int* row_ptr = (int*)alloc((size_t)(N + 1) * 4);
  int2* edge = (int2*)alloc((size_t)P * 8);
  float* wedot = (float*)alloc(16 * 4);
  float* al_s = (float*)alloc((size_t)N * 4 * 4);
  float* al_d = (float*)alloc((size_t)N * 4 * 4);
  unsigned short* Wf1 = (unsigned short*)alloc((size_t)17 * 4096 * 2);
  unsigned short* Wf2 = (unsigned short*)alloc((size_t)5 * 4096 * 2);
  unsigned short* bufA = (unsigned short*)alloc((size_t)N * 256 * 2);  // agg out
  unsigned short* bufB = (unsigned short*)alloc((size_t)N * 256 * 2);  // gemm out
  (void)ws_size;

  hipMemsetAsync(d_ws, 0, zero_bytes, stream);

  int gE = (E + 255) / 256;
  int gP = (P + 255) / 256;
  int gD = (N + 255) / 256;

  k1_kernel<<<353 + gD + gE, 256, 0, stream>>>(
      x, dstv, eattr, W0, as0, ad0, We0, ae0, W1, as1, ad1, We1, ae1,
      W2, as2, ad2, We2, ae2, Wf1, Wf2, wedot, al_s, al_d, deg, asum, N, E, gD);
  scan_kernel<<<1, 1024, 0, stream>>>(deg, row_ptr, N);
  fill_kernel<<<gP, 256, 0, stream>>>(srcv, dstv, eattr, row_ptr, deg, asum, fill, edge, E, N);

  int gStrip = (N + 15) / 16;
  int gNode4 = (N + 3) / 4;

  // ---- layer 0: aggregate x then project (fused)
  agg0_kernel<<<gNode4, 256, 0, stream>>>(row_ptr, edge, al_s, al_d, wedot, x, W0, b0, bufA, N);

  // ---- layer 1
  mfma_gemm_dots<256, 4><<<gStrip, 64, 0, stream>>>(bufA, Wf1, bufB, al_s, al_d, N);
  agg4_kernel<<<gNode4, 256, 0, stream>>>(row_ptr, edge, al_s, al_d, wedot + 4, bufB, b1, bufA, N);

  // ---- layer 2 (+ LayerNorm -> d_out)
  mfma_gemm_dots<64, 1><<<gStrip, 64, 0, stream>>>(bufA, Wf2, bufB, al_s, al_d, N);
  agg_ln_kernel<<<gNode4, 256, 0, stream>>>(row_ptr, edge, al_s, al_d, wedot + 8, bufB, b2,
                                            lng, lnb, outp, N);
}

// Round 10
// 284.745 us; speedup vs baseline: 1.0098x; 1.0098x over previous
//
#include <hip/hip_runtime.h>
#include <hip/hip_bf16.h>
#include <hip/hip_fp16.h>
#include <math.h>

// GAT x3 + LayerNorm for MI355X (gfx950).
// R10: edge weights precomputed edge-parallel (ew4/ew1) and packed with src
// into one record ({src, 4xfp16 w} int4 / {src, f32 w} int2). Agg loops are
// now pure rec->row->fma (no al gather, no exp): agg4 1.5 instr/edge,
// agg0 0.5 instr/edge (lane=(edge-slot,channel), 4 edges per instr),
// agg_ln 1.25 instr/edge. Carried: bf16 h, al = A @ va via extra MFMA
// col-tile, layer-0 aggregate-then-project, merged prep, single-pass scan.

typedef __attribute__((ext_vector_type(8))) short short8;
typedef __attribute__((ext_vector_type(4))) float float4v;

__device__ __forceinline__ float wave_sum(float v) {
#pragma unroll
  for (int off = 32; off > 0; off >>= 1) v += __shfl_xor(v, off, 64);
  return v;
}

__device__ __forceinline__ unsigned short f2bf(float v) {
  unsigned u = __float_as_uint(v);
  unsigned r = u + 0x7fff + ((u >> 16) & 1);  // RNE
  return (unsigned short)(r >> 16);
}

__device__ __forceinline__ float bf2f(unsigned short u) {
  return __uint_as_float(((unsigned)u) << 16);
}

__device__ __forceinline__ int h2i(__half2 h) {
  int i;
  __builtin_memcpy(&i, &h, 4);
  return i;
}
__device__ __forceinline__ __half2 i2h(int i) {
  __half2 h;
  __builtin_memcpy(&h, &i, 4);
  return h;
}

// ---------------- K1 mega-dispatch ----------------
// blocks [0,272): Wf1 (16 W1-tiles + 1 va1 tile, bf16 fragment order)
// blocks [272,352): Wf2 (4 W2-tiles + 1 va2 tile)
// block 352: wedot[0..8]
// blocks [353, 353+gD): layer-0 dots (va0 built per block in LDS)
// blocks [353+gD, ...): degree histogram + edge_attr sums
__global__ __launch_bounds__(256) void k1_kernel(
    const float* __restrict__ x, const int* __restrict__ dstv, const float* __restrict__ eattr,
    const float* __restrict__ W0, const float* __restrict__ as0, const float* __restrict__ ad0,
    const float* __restrict__ We0, const float* __restrict__ ae0,
    const float* __restrict__ W1, const float* __restrict__ as1, const float* __restrict__ ad1,
    const float* __restrict__ We1, const float* __restrict__ ae1,
    const float* __restrict__ W2, const float* __restrict__ as2, const float* __restrict__ ad2,
    const float* __restrict__ We2, const float* __restrict__ ae2,
    unsigned short* __restrict__ Wf1, unsigned short* __restrict__ Wf2,
    float* __restrict__ wedot, float* __restrict__ al_s, float* __restrict__ al_d,
    int* __restrict__ deg, float* __restrict__ asum, int N, int E, int gD) {
  int b = blockIdx.x;
  int tid = threadIdx.x;
  if (b < 272) {  // Wf1
    int idx = b * 256 + tid;
    int j = idx & 7, lane = (idx >> 3) & 63, ks = (idx >> 9) & 7, nt = idx >> 12;
    int k = ks * 32 + (lane >> 4) * 8 + j;
    int col = lane & 15;
    float v = 0.f;
    if (nt < 16) {
      v = W1[(size_t)k * 256 + nt * 16 + col];
    } else if (col < 4) {
      for (int c = 0; c < 64; c++) v = fmaf(W1[(size_t)k * 256 + col * 64 + c], as1[col * 64 + c], v);
    } else if (col < 8) {
      int h = col - 4;
      for (int c = 0; c < 64; c++) v = fmaf(W1[(size_t)k * 256 + h * 64 + c], ad1[h * 64 + c], v);
    }
    Wf1[idx] = f2bf(v);
  } else if (b < 352) {  // Wf2
    int idx = (b - 272) * 256 + tid;
    int j = idx & 7, lane = (idx >> 3) & 63, ks = (idx >> 9) & 7, nt = idx >> 12;
    int k = ks * 32 + (lane >> 4) * 8 + j;
    int col = lane & 15;
    float v = 0.f;
    if (nt < 4) {
      v = W2[(size_t)k * 64 + nt * 16 + col];
    } else if (col < 1) {
      for (int c = 0; c < 64; c++) v = fmaf(W2[(size_t)k * 64 + c], as2[c], v);
    } else if (col < 2) {
      for (int c = 0; c < 64; c++) v = fmaf(W2[(size_t)k * 64 + c], ad2[c], v);
    }
    Wf2[idx] = f2bf(v);
  } else if (b == 352) {  // wedot
    if (tid >= 64) return;
    int c = tid;
    for (int h = 0; h < 4; h++) {
      float v = wave_sum(We0[h * 64 + c] * ae0[h * 64 + c]);
      if (c == 0) wedot[h] = v;
    }
    for (int h = 0; h < 4; h++) {
      float v = wave_sum(We1[h * 64 + c] * ae1[h * 64 + c]);
      if (c == 0) wedot[4 + h] = v;
    }
    float v = wave_sum(We2[c] * ae2[c]);
    if (c == 0) wedot[8] = v;
  } else if (b < 353 + gD) {  // layer-0 dots: al = x @ va0
    __shared__ float va[128];  // [k*8 + col], col<4: as, col in [4,8): ad
    if (tid < 128) {
      int k = tid >> 3, col = tid & 7;
      float v = 0.f;
      if (col < 4) {
        for (int c = 0; c < 64; c++) v = fmaf(W0[(size_t)k * 256 + col * 64 + c], as0[col * 64 + c], v);
      } else {
        int h = col - 4;
        for (int c = 0; c < 64; c++) v = fmaf(W0[(size_t)k * 256 + h * 64 + c], ad0[h * 64 + c], v);
      }
      va[tid] = v;
    }
    __syncthreads();
    int node = (b - 353) * 256 + tid;
    if (node >= N) return;
    const float4* xr = (const float4*)(x + (size_t)node * 16);
    float4 xv[4];
#pragma unroll
    for (int q = 0; q < 4; q++) xv[q] = xr[q];
    float al[8];
#pragma unroll
    for (int j = 0; j < 8; j++) al[j] = 0.f;
#pragma unroll
    for (int k = 0; k < 16; k++) {
      float xk = ((const float*)xv)[k];
#pragma unroll
      for (int j = 0; j < 8; j++) al[j] = fmaf(xk, va[k * 8 + j], al[j]);
    }
    ((float4*)al_s)[node] = make_float4(al[0], al[1], al[2], al[3]);
    ((float4*)al_d)[node] = make_float4(al[4], al[5], al[6], al[7]);
  } else {  // degree histogram
    int e = (b - 353 - gD) * 256 + tid;
    if (e >= E) return;
    int d = dstv[e];
    atomicAdd(&deg[d], 1);
    atomicAdd(&asum[d], eattr[e]);
  }
}

// Single-pass scan: thread t owns C contiguous nodes.
__global__ __launch_bounds__(1024) void scan_kernel(const int* __restrict__ deg,
                                                    int* __restrict__ row_ptr, int n) {
  int tid = threadIdx.x, wid = tid >> 6, lane = tid & 63;
  int C = (n + 1023) >> 10;
  int base = tid * C;
  int sum = 0;
  for (int j = 0; j < C; j++) {
    int i = base + j;
    if (i < n) sum += deg[i] + 1;
  }
  int sc = sum;
#pragma unroll
  for (int off = 1; off < 64; off <<= 1) {
    int t = __shfl_up(sc, off, 64);
    if (lane >= off) sc += t;
  }
  __shared__ int wtot[16], wexc[16];
  __shared__ int total;
  if (lane == 63) wtot[wid] = sc;
  __syncthreads();
  if (tid == 0) {
    int run = 0;
#pragma unroll
    for (int i = 0; i < 16; i++) { int t = wtot[i]; wexc[i] = run; run += t; }
    total = run;
  }
  __syncthreads();
  int run = wexc[wid] + (sc - sum);
  for (int j = 0; j < C; j++) {
    int i = base + j;
    if (i < n) {
      row_ptr[i] = run;
      run += deg[i] + 1;
    }
  }
  if (tid == 0) row_ptr[n] = total;
}

// Merged CSR fill (+ dstpos): t<E scatters real edges; t>=E appends self loop.
__global__ void fill_kernel(const int* __restrict__ src, const int* __restrict__ dst,
                            const float* __restrict__ eattr, const int* __restrict__ row_ptr,
                            const int* __restrict__ deg, const float* __restrict__ asum,
                            int* __restrict__ fill, int2* __restrict__ edge,
                            int* __restrict__ dstpos, int E, int n) {
  int t = blockIdx.x * 256 + threadIdx.x;
  if (t < E) {
    int d = dst[t];
    int pos = row_ptr[d] + atomicAdd(&fill[d], 1);
    edge[pos] = make_int2(src[t], __float_as_int(eattr[t]));
    dstpos[pos] = d;
  } else {
    int i = t - E;
    if (i < n) {
      int dg = deg[i];
      int pos = row_ptr[i] + dg;
      edge[pos] = make_int2(i, __float_as_int(asum[i] / fmaxf((float)dg, 1.f)));
      dstpos[pos] = i;
    }
  }
}

// Edge-parallel weights, H=4: wrec[p] = {src, h2(w0,w1), h2(w2,w3), 0}.
// Softmax max cancels in the ratio; clamp 11 keeps e^a < fp16 max (65504).
__global__ void ew4_kernel(const int2* __restrict__ edge, const int* __restrict__ dstpos,
                           const float* __restrict__ al_s, const float* __restrict__ al_d,
                           const float* __restrict__ wedot, int4* __restrict__ wrec, int P) {
  int p = blockIdx.x * 256 + threadIdx.x;
  if (p >= P) return;
  int2 g = edge[p];
  int d = dstpos[p];
  float ev = __int_as_float(g.y);
  float4 as4 = ((const float4*)al_s)[g.x];
  float4 ad4 = ((const float4*)al_d)[d];
  float w[4];
#pragma unroll
  for (int h = 0; h < 4; h++) {
    float a = ((const float*)&as4)[h] + ((const float*)&ad4)[h] + ev * wedot[h];
    a = fmaxf(a, 0.2f * a);
    a = fminf(a, 11.f);
    w[h] = __expf(a);
  }
  __half2 p01 = __floats2half2_rn(w[0], w[1]);
  __half2 p23 = __floats2half2_rn(w[2], w[3]);
  wrec[p] = make_int4(g.x, h2i(p01), h2i(p23), 0);
}

// Edge-parallel weights, H=1: wrec[p] = {src, f32 w}.
__global__ void ew1_kernel(const int2* __restrict__ edge, const int* __restrict__ dstpos,
                           const float* __restrict__ al_s, const float* __restrict__ al_d,
                           const float* __restrict__ wedot, int2* __restrict__ wrec, int P) {
  int p = blockIdx.x * 256 + threadIdx.x;
  if (p >= P) return;
  int2 g = edge[p];
  int d = dstpos[p];
  float a = al_s[g.x] + al_d[d] + __int_as_float(g.y) * wedot[0];
  a = fmaxf(a, 0.2f * a);
  a = fminf(a, 30.f);
  wrec[p] = make_int2(g.x, __float_as_int(__expf(a)));
}

// Layer-0 fused aggregate-then-project: one wave per node.
// Lane = (es, c): es = edge sub-slot 0..3, c = x channel 0..15. One rec instr
// and one x-row instr cover FOUR edges. Z[h] per lane = partial sum for
// (h, c) over edges es+4k; reduced over es by shfl_xor(16,32). Projection
// epilogue (16->256 with W0 fragment in registers) + bias + ELU; bf16 out.
__global__ __launch_bounds__(256) void agg0_kernel(
    const int* __restrict__ row_ptr, const int4* __restrict__ wrec,
    const float* __restrict__ x, const float* __restrict__ W0,
    const float* __restrict__ bias, unsigned short* __restrict__ out, int n) {
  int node = blockIdx.x * 4 + (threadIdx.x >> 6);
  if (node >= n) return;
  int lane = threadIdx.x & 63;
  int es = lane >> 4;
  int c = lane & 15;
  int beg = row_ptr[node], end = row_ptr[node + 1];
  int cnt = end - beg;
  float Z[4] = {0.f, 0.f, 0.f, 0.f};
  float den[4] = {0.f, 0.f, 0.f, 0.f};
  for (int i = 0; i < cnt; i += 4) {
    int idx = i + es;
    bool valid = idx < cnt;
    int4 r = wrec[valid ? (beg + idx) : (end - 1)];
    float xv = x[(size_t)r.x * 16 + c];
    __half2 p01 = i2h(r.y), p23 = i2h(r.z);
    float w0 = __low2float(p01), w1 = __high2float(p01);
    float w2 = __low2float(p23), w3 = __high2float(p23);
    if (!valid) { w0 = 0.f; w1 = 0.f; w2 = 0.f; w3 = 0.f; }
    den[0] += w0;
    den[1] += w1;
    den[2] += w2;
    den[3] += w3;
    Z[0] = fmaf(w0, xv, Z[0]);
    Z[1] = fmaf(w1, xv, Z[1]);
    Z[2] = fmaf(w2, xv, Z[2]);
    Z[3] = fmaf(w3, xv, Z[3]);
  }
#pragma unroll
  for (int h = 0; h < 4; h++) {
    Z[h] += __shfl_xor(Z[h], 16, 64);
    Z[h] += __shfl_xor(Z[h], 32, 64);
    den[h] += __shfl_xor(den[h], 16, 64);
    den[h] += __shfl_xor(den[h], 32, 64);
  }
  // reinterpret lane as (h, c): every lane now holds total Z[h][c] for its c
  int h = es;
  float zsel = (h == 0) ? Z[0] : (h == 1) ? Z[1] : (h == 2) ? Z[2] : Z[3];
  float dsel = (h == 0) ? den[0] : (h == 1) ? den[1] : (h == 2) ? den[2] : den[3];
  float zn = zsel / (dsel + 1e-16f);
  // projection: out[4*lane + jj] = bias + sum_cc Zn[h][cc] * W0[cc][4*lane+jj]
  float4 w0r[16];
#pragma unroll
  for (int cc = 0; cc < 16; cc++) w0r[cc] = ((const float4*)(W0 + (size_t)cc * 256))[lane];
  float zc[16];
  int basel = lane & 48;  // h*16
#pragma unroll
  for (int cc = 0; cc < 16; cc++) zc[cc] = __shfl(zn, basel + cc, 64);
  float o[4];
  float4 b4 = ((const float4*)bias)[lane];
#pragma unroll
  for (int jj = 0; jj < 4; jj++) o[jj] = ((const float*)&b4)[jj];
#pragma unroll
  for (int cc = 0; cc < 16; cc++) {
#pragma unroll
    for (int jj = 0; jj < 4; jj++) o[jj] = fmaf(zc[cc], ((const float*)&w0r[cc])[jj], o[jj]);
  }
  ushort4 o4;
  float ox = o[0] > 0.f ? o[0] : expm1f(o[0]);
  float oy = o[1] > 0.f ? o[1] : expm1f(o[1]);
  float oz = o[2] > 0.f ? o[2] : expm1f(o[2]);
  float ow = o[3] > 0.f ? o[3] : expm1f(o[3]);
  o4.x = f2bf(ox);
  o4.y = f2bf(oy);
  o4.z = f2bf(oz);
  o4.w = f2bf(ow);
  ((ushort4*)out)[(size_t)node * 64 + lane] = o4;
}

// bf16 MFMA GEMM (K=256): bf16 out; al_s/al_d from the extra va col-tile.
template <int M, int H>
__global__ __launch_bounds__(64) void mfma_gemm_dots(
    const unsigned short* __restrict__ Abf, const unsigned short* __restrict__ Wfrag,
    unsigned short* __restrict__ out, float* __restrict__ al_s, float* __restrict__ al_d,
    int n) {
  int lane = threadIdx.x;
  int row0 = blockIdx.x * 16;
  int m = lane & 15, q = lane >> 4;

  short8 afrag[8];
  int r = row0 + m;
  if (r < n) {
    const short8* arow = (const short8*)(Abf + (size_t)r * 256);
#pragma unroll
    for (int ks = 0; ks < 8; ks++) afrag[ks] = arow[ks * 4 + q];
  } else {
#pragma unroll
    for (int ks = 0; ks < 8; ks++) afrag[ks] = (short8)0;
  }

  const short8* wf = (const short8*)Wfrag;

  auto epi = [&](int tile, float4v acc) {
    int col = tile * 16 + m;
#pragma unroll
    for (int reg = 0; reg < 4; reg++) {
      int rr = row0 + q * 4 + reg;
      if (rr < n) out[(size_t)rr * M + col] = f2bf(acc[reg]);
    }
  };

  for (int nt = 0; nt < M / 16; nt += 2) {
    const short8* b0 = wf + (size_t)nt * 8 * 64 + lane;
    const short8* b1 = b0 + 8 * 64;
    short8 bf0[8], bf1[8];
#pragma unroll
    for (int ks = 0; ks < 8; ks++) {
      bf0[ks] = b0[ks * 64];
      bf1[ks] = b1[ks * 64];
    }
    float4v acc0 = {0.f, 0.f, 0.f, 0.f};
    float4v acc1 = {0.f, 0.f, 0.f, 0.f};
#pragma unroll
    for (int ks = 0; ks < 8; ks++) {
      acc0 = __builtin_amdgcn_mfma_f32_16x16x32_bf16(afrag[ks], bf0[ks], acc0, 0, 0, 0);
      acc1 = __builtin_amdgcn_mfma_f32_16x16x32_bf16(afrag[ks], bf1[ks], acc1, 0, 0, 0);
    }
    epi(nt, acc0);
    epi(nt + 1, acc1);
  }

  // va tile -> al_s / al_d
  {
    const short8* bl = wf + (size_t)(M / 16) * 8 * 64 + lane;
    short8 bf[8];
#pragma unroll
    for (int ks = 0; ks < 8; ks++) bf[ks] = bl[ks * 64];
    float4v acc = {0.f, 0.f, 0.f, 0.f};
#pragma unroll
    for (int ks = 0; ks < 8; ks++)
      acc = __builtin_amdgcn_mfma_f32_16x16x32_bf16(afrag[ks], bf[ks], acc, 0, 0, 0);
#pragma unroll
    for (int reg = 0; reg < 4; reg++) {
      int rr = row0 + q * 4 + reg;
      if (rr < n) {
        if (m < H) al_s[(size_t)rr * H + m] = acc[reg];
        else if (m < 2 * H) al_d[(size_t)rr * H + (m - H)] = acc[reg];
      }
    }
  }
}

// H=4 aggregation: one wave per node, TWO edge streams (lanes 0-31 / 32-63);
// lane holds channels l*8..l*8+7. Per edge: 1 uniform dwordx4 wrec load +
// 0.5 row instrs. No exp, no al gather. bias+ELU fused; bf16 out.
__global__ __launch_bounds__(256) void agg4_kernel(
    const int* __restrict__ row_ptr, const int4* __restrict__ wrec,
    const unsigned short* __restrict__ B, const float* __restrict__ bias,
    unsigned short* __restrict__ out, int n) {
  int node = blockIdx.x * 4 + (threadIdx.x >> 6);
  if (node >= n) return;
  int lane = threadIdx.x & 63;
  int half = lane >> 5;
  int l = lane & 31;
  int h4 = l >> 3;
  int beg = row_ptr[node], end = row_ptr[node + 1];
  int cnt = end - beg;
  int cntA = (cnt + 1) >> 1;
  int myCnt = half ? (cnt - cntA) : cntA;
  int myBeg = half ? (beg + cntA) : beg;

  float acc[8];
#pragma unroll
  for (int j = 0; j < 8; j++) acc[j] = 0.f;
  float den = 0.f;

  for (int i = 0; i < cntA; i += 4) {
    int4 r[4];
    short8 bv[4];
    bool val[4];
#pragma unroll
    for (int t = 0; t < 4; t++) {
      val[t] = (i + t) < myCnt;
      r[t] = wrec[val[t] ? (myBeg + i + t) : (end - 1)];
    }
#pragma unroll
    for (int t = 0; t < 4; t++) bv[t] = ((const short8*)(B + (size_t)r[t].x * 256))[l];
#pragma unroll
    for (int t = 0; t < 4; t++) {
      int wdw = (h4 < 2) ? r[t].y : r[t].z;
      __half2 hh2 = i2h(wdw);
      float w = (h4 & 1) ? __high2float(hh2) : __low2float(hh2);
      w = val[t] ? w : 0.f;
      den += w;
      const unsigned short* bp = (const unsigned short*)&bv[t];
#pragma unroll
      for (int j = 0; j < 8; j++) acc[j] = fmaf(w, bf2f(bp[j]), acc[j]);
    }
  }

  den += __shfl_xor(den, 32, 64);
#pragma unroll
  for (int j = 0; j < 8; j++) acc[j] += __shfl_xor(acc[j], 32, 64);

  if (half == 0) {
    float inv = 1.f / (den + 1e-16f);
    float4 b0 = ((const float4*)bias)[l * 2];
    float4 b1 = ((const float4*)bias)[l * 2 + 1];
    unsigned short o8[8];
#pragma unroll
    for (int j = 0; j < 8; j++) {
      float bjv = (j < 4) ? ((const float*)&b0)[j] : ((const float*)&b1)[j - 4];
      float o = acc[j] * inv + bjv;
      o = o > 0.f ? o : expm1f(o);
      o8[j] = f2bf(o);
    }
    ((short8*)(out + (size_t)node * 256))[l] = *(short8*)o8;
  }
}

// H=1 aggregation + bias + LayerNorm: one wave per node, FOUR edge streams;
// per edge: 1 uniform int2 wrec load + 0.25 row instrs.
__global__ __launch_bounds__(256) void agg_ln_kernel(
    const int* __restrict__ row_ptr, const int2* __restrict__ wrec,
    const unsigned short* __restrict__ B, const float* __restrict__ bias,
    const float* __restrict__ ln_g, const float* __restrict__ ln_b,
    float* __restrict__ out, int n) {
  int node = blockIdx.x * 4 + (threadIdx.x >> 6);
  if (node >= n) return;
  int lane = threadIdx.x & 63;
  int q = lane >> 4;
  int l = lane & 15;
  int beg = row_ptr[node], end = row_ptr[node + 1];
  int cnt = end - beg;
  int base = cnt >> 2, rem = cnt & 3;
  int myCnt = base + (q < rem ? 1 : 0);
  int myBeg = beg + q * base + min(q, rem);
  int iters = base + (rem ? 1 : 0);

  float4 acc = make_float4(0.f, 0.f, 0.f, 0.f);
  float den = 0.f;

  for (int i = 0; i < iters; i += 2) {
    int2 r[2];
    ushort4 bv[2];
    bool val[2];
#pragma unroll
    for (int t = 0; t < 2; t++) {
      val[t] = (i + t) < myCnt;
      r[t] = wrec[val[t] ? (myBeg + i + t) : (end - 1)];
    }
#pragma unroll
    for (int t = 0; t < 2; t++) bv[t] = ((const ushort4*)(B + (size_t)r[t].x * 64))[l];
#pragma unroll
    for (int t = 0; t < 2; t++) {
      float w = val[t] ? __int_as_float(r[t].y) : 0.f;
      den += w;
      acc.x = fmaf(w, bf2f(bv[t].x), acc.x);
      acc.y = fmaf(w, bf2f(bv[t].y), acc.y);
      acc.z = fmaf(w, bf2f(bv[t].z), acc.z);
      acc.w = fmaf(w, bf2f(bv[t].w), acc.w);
    }
  }

  den += __shfl_xor(den, 32, 64);
  den += __shfl_xor(den, 16, 64);
  acc.x += __shfl_xor(acc.x, 32, 64);
  acc.y += __shfl_xor(acc.y, 32, 64);
  acc.z += __shfl_xor(acc.z, 32, 64);
  acc.w += __shfl_xor(acc.w, 32, 64);
  acc.x += __shfl_xor(acc.x, 16, 64);
  acc.y += __shfl_xor(acc.y, 16, 64);
  acc.z += __shfl_xor(acc.z, 16, 64);
  acc.w += __shfl_xor(acc.w, 16, 64);

  float inv = 1.f / (den + 1e-16f);
  float4 b4 = ((const float4*)bias)[l];
  float4 o;
  o.x = acc.x * inv + b4.x;
  o.y = acc.y * inv + b4.y;
  o.z = acc.z * inv + b4.z;
  o.w = acc.w * inv + b4.w;
  float s = (o.x + o.y) + (o.z + o.w);
#pragma unroll
  for (int off = 1; off < 16; off <<= 1) s += __shfl_xor(s, off, 64);
  float mu = s * (1.f / 64.f);
  float dx = o.x - mu, dy = o.y - mu, dz = o.z - mu, dw = o.w - mu;
  float v = (dx * dx + dy * dy) + (dz * dz + dw * dw);
#pragma unroll
  for (int off = 1; off < 16; off <<= 1) v += __shfl_xor(v, off, 64);
  float rs = rsqrtf(v * (1.f / 64.f) + 1e-5f);
  if (q == 0) {
    float4 g4 = ((const float4*)ln_g)[l];
    float4 lb4 = ((const float4*)ln_b)[l];
    float4 rr;
    rr.x = dx * rs * g4.x + lb4.x;
    rr.y = dy * rs * g4.y + lb4.y;
    rr.z = dz * rs * g4.z + lb4.z;
    rr.w = dw * rs * g4.w + lb4.w;
    ((float4*)(out + (size_t)node * 64))[l] = rr;
  }
}

extern "C" void kernel_launch(void* const* d_in, const int* in_sizes, int n_in,
                              void* d_out, int out_size, void* d_ws, size_t ws_size,
                              hipStream_t stream) {
  const float* x = (const float*)d_in[0];
  const int* ei = (const int*)d_in[1];
  const float* eattr = (const float*)d_in[2];
  const float* W0 = (const float*)d_in[3];
  const float* as0 = (const float*)d_in[4];
  const float* ad0 = (const float*)d_in[5];
  const float* We0 = (const float*)d_in[6];
  const float* ae0 = (const float*)d_in[7];
  const float* b0 = (const float*)d_in[8];
  const float* W1 = (const float*)d_in[9];
  const float* as1 = (const float*)d_in[10];
  const float* ad1 = (const float*)d_in[11];
  const float* We1 = (const float*)d_in[12];
  const float* ae1 = (const float*)d_in[13];
  const float* b1 = (const float*)d_in[14];
  const float* W2 = (const float*)d_in[15];
  const float* as2 = (const float*)d_in[16];
  const float* ad2 = (const float*)d_in[17];
  const float* We2 = (const float*)d_in[18];
  const float* ae2 = (const float*)d_in[19];
  const float* b2 = (const float*)d_in[20];
  const float* lng = (const float*)d_in[21];
  const float* lnb = (const float*)d_in[22];
  float* outp = (float*)d_out;

  const int N = in_sizes[0] / 16;
  const int E = in_sizes[1] / 2;
  const int P = E + N;
  const int* srcv = ei;
  const int* dstv = ei + E;

  char* w = (char*)d_ws;
  size_t off = 0;
  auto alloc = [&](size_t bytes) -> void* {
    void* p = w + off;
    off += (bytes + 255) & ~(size_t)255;
    return p;
  };
  int* deg = (int*)alloc((size_t)N * 4);
  float* asum = (float*)alloc((size_t)N * 4);
  int* fill = (int*)alloc((size_t)N * 4);
  size_t zero_bytes = off;
  int* row_ptr = (int*)alloc((size_t)(N + 1) * 4);
  int2* edge = (int2*)alloc((size_t)P * 8);
  int* dstpos = (int*)alloc((size_t)P * 4);
  int4* wrec4 = (int4*)alloc((size_t)P * 16);
  int2* wrec1 = (int2*)wrec4;  // alias (sequential use)
  float* wedot = (float*)alloc(16 * 4);
  float* al_s = (float*)alloc((size_t)N * 4 * 4);
  float* al_d = (float*)alloc((size_t)N * 4 * 4);
  unsigned short* Wf1 = (unsigned short*)alloc((size_t)17 * 4096 * 2);
  unsigned short* Wf2 = (unsigned short*)alloc((size_t)5 * 4096 * 2);
  unsigned short* bufA = (unsigned short*)alloc((size_t)N * 256 * 2);  // agg out
  unsigned short* bufB = (unsigned short*)alloc((size_t)N * 256 * 2);  // gemm out
  (void)ws_size;

  hipMemsetAsync(d_ws, 0, zero_bytes, stream);

  int gE = (E + 255) / 256;
  int gP = (P + 255) / 256;
  int gD = (N + 255) / 256;

  k1_kernel<<<353 + gD + gE, 256, 0, stream>>>(
      x, dstv, eattr, W0, as0, ad0, We0, ae0, W1, as1, ad1, We1, ae1,
      W2, as2, ad2, We2, ae2, Wf1, Wf2, wedot, al_s, al_d, deg, asum, N, E, gD);
  scan_kernel<<<1, 1024, 0, stream>>>(deg, row_ptr, N);
  fill_kernel<<<gP, 256, 0, stream>>>(srcv, dstv, eattr, row_ptr, deg, asum, fill,
                                      edge, dstpos, E, N);

  int gStrip = (N + 15) / 16;
  int gNode4 = (N + 3) / 4;

  // ---- layer 0: edge weights, then aggregate x + project (fused)
  ew4_kernel<<<gP, 256, 0, stream>>>(edge, dstpos, al_s, al_d, wedot, wrec4, P);
  agg0_kernel<<<gNode4, 256, 0, stream>>>(row_ptr, wrec4, x, W0, b0, bufA, N);

  // ---- layer 1
  mfma_gemm_dots<256, 4><<<gStrip, 64, 0, stream>>>(bufA, Wf1, bufB, al_s, al_d, N);
  ew4_kernel<<<gP, 256, 0, stream>>>(edge, dstpos, al_s, al_d, wedot + 4, wrec4, P);
  agg4_kernel<<<gNode4, 256, 0, stream>>>(row_ptr, wrec4, bufB, b1, bufA, N);

  // ---- layer 2 (+ LayerNorm -> d_out)
  mfma_gemm_dots<64, 1><<<gStrip, 64, 0, stream>>>(bufA, Wf2, bufB, al_s, al_d, N);
  ew1_kernel<<<gP, 256, 0, stream>>>(edge, dstpos, al_s, al_d, wedot + 8, wrec1, P);
  agg_ln_kernel<<<gNode4, 256, 0, stream>>>(row_ptr, wrec1, bufB, b2, lng, lnb, outp, N);
}

// Round 11
// 282.390 us; speedup vs baseline: 1.0182x; 1.0083x over previous
//
#include <hip/hip_runtime.h>
#include <hip/hip_bf16.h>
#include <hip/hip_fp16.h>
#include <math.h>

// GAT x3 + LayerNorm for MI355X (gfx950).
// R11: wave-uniform edge-record reads moved to the SCALAR path (s_load via
// readfirstlane) in all three aggregation kernels -> ~3x fewer TA lane-
// addresses per edge (the R4/R8/R10-resistant floor). Lanes select src/w from
// SGPRs via cndmask. wrec padded +8 for tail overread; invalid slots clamped.
// Carried: bf16 h, edge-parallel packed weights (ew4/ew1), al = A @ va via
// extra MFMA col-tile, layer-0 aggregate-then-project, merged prep, 1-pass scan.

typedef __attribute__((ext_vector_type(8))) short short8;
typedef __attribute__((ext_vector_type(4))) float float4v;

__device__ __forceinline__ float wave_sum(float v) {
#pragma unroll
  for (int off = 32; off > 0; off >>= 1) v += __shfl_xor(v, off, 64);
  return v;
}

__device__ __forceinline__ unsigned short f2bf(float v) {
  unsigned u = __float_as_uint(v);
  unsigned r = u + 0x7fff + ((u >> 16) & 1);  // RNE
  return (unsigned short)(r >> 16);
}

__device__ __forceinline__ float bf2f(unsigned short u) {
  return __uint_as_float(((unsigned)u) << 16);
}

__device__ __forceinline__ int h2i(__half2 h) {
  int i;
  __builtin_memcpy(&i, &h, 4);
  return i;
}
__device__ __forceinline__ __half2 i2h(int i) {
  __half2 h;
  __builtin_memcpy(&h, &i, 4);
  return h;
}

// ---------------- K1 mega-dispatch ----------------
__global__ __launch_bounds__(256) void k1_kernel(
    const float* __restrict__ x, const int* __restrict__ dstv, const float* __restrict__ eattr,
    const float* __restrict__ W0, const float* __restrict__ as0, const float* __restrict__ ad0,
    const float* __restrict__ We0, const float* __restrict__ ae0,
    const float* __restrict__ W1, const float* __restrict__ as1, const float* __restrict__ ad1,
    const float* __restrict__ We1, const float* __restrict__ ae1,
    const float* __restrict__ W2, const float* __restrict__ as2, const float* __restrict__ ad2,
    const float* __restrict__ We2, const float* __restrict__ ae2,
    unsigned short* __restrict__ Wf1, unsigned short* __restrict__ Wf2,
    float* __restrict__ wedot, float* __restrict__ al_s, float* __restrict__ al_d,
    int* __restrict__ deg, float* __restrict__ asum, int N, int E, int gD) {
  int b = blockIdx.x;
  int tid = threadIdx.x;
  if (b < 272) {  // Wf1: 16 W1-tiles + 1 va1 tile, bf16 fragment order
    int idx = b * 256 + tid;
    int j = idx & 7, lane = (idx >> 3) & 63, ks = (idx >> 9) & 7, nt = idx >> 12;
    int k = ks * 32 + (lane >> 4) * 8 + j;
    int col = lane & 15;
    float v = 0.f;
    if (nt < 16) {
      v = W1[(size_t)k * 256 + nt * 16 + col];
    } else if (col < 4) {
      for (int c = 0; c < 64; c++) v = fmaf(W1[(size_t)k * 256 + col * 64 + c], as1[col * 64 + c], v);
    } else if (col < 8) {
      int h = col - 4;
      for (int c = 0; c < 64; c++) v = fmaf(W1[(size_t)k * 256 + h * 64 + c], ad1[h * 64 + c], v);
    }
    Wf1[idx] = f2bf(v);
  } else if (b < 352) {  // Wf2: 4 W2-tiles + 1 va2 tile
    int idx = (b - 272) * 256 + tid;
    int j = idx & 7, lane = (idx >> 3) & 63, ks = (idx >> 9) & 7, nt = idx >> 12;
    int k = ks * 32 + (lane >> 4) * 8 + j;
    int col = lane & 15;
    float v = 0.f;
    if (nt < 4) {
      v = W2[(size_t)k * 64 + nt * 16 + col];
    } else if (col < 1) {
      for (int c = 0; c < 64; c++) v = fmaf(W2[(size_t)k * 64 + c], as2[c], v);
    } else if (col < 2) {
      for (int c = 0; c < 64; c++) v = fmaf(W2[(size_t)k * 64 + c], ad2[c], v);
    }
    Wf2[idx] = f2bf(v);
  } else if (b == 352) {  // wedot
    if (tid >= 64) return;
    int c = tid;
    for (int h = 0; h < 4; h++) {
      float v = wave_sum(We0[h * 64 + c] * ae0[h * 64 + c]);
      if (c == 0) wedot[h] = v;
    }
    for (int h = 0; h < 4; h++) {
      float v = wave_sum(We1[h * 64 + c] * ae1[h * 64 + c]);
      if (c == 0) wedot[4 + h] = v;
    }
    float v = wave_sum(We2[c] * ae2[c]);
    if (c == 0) wedot[8] = v;
  } else if (b < 353 + gD) {  // layer-0 dots: al = x @ va0
    __shared__ float va[128];
    if (tid < 128) {
      int k = tid >> 3, col = tid & 7;
      float v = 0.f;
      if (col < 4) {
        for (int c = 0; c < 64; c++) v = fmaf(W0[(size_t)k * 256 + col * 64 + c], as0[col * 64 + c], v);
      } else {
        int h = col - 4;
        for (int c = 0; c < 64; c++) v = fmaf(W0[(size_t)k * 256 + h * 64 + c], ad0[h * 64 + c], v);
      }
      va[tid] = v;
    }
    __syncthreads();
    int node = (b - 353) * 256 + tid;
    if (node >= N) return;
    const float4* xr = (const float4*)(x + (size_t)node * 16);
    float4 xv[4];
#pragma unroll
    for (int q = 0; q < 4; q++) xv[q] = xr[q];
    float al[8];
#pragma unroll
    for (int j = 0; j < 8; j++) al[j] = 0.f;
#pragma unroll
    for (int k = 0; k < 16; k++) {
      float xk = ((const float*)xv)[k];
#pragma unroll
      for (int j = 0; j < 8; j++) al[j] = fmaf(xk, va[k * 8 + j], al[j]);
    }
    ((float4*)al_s)[node] = make_float4(al[0], al[1], al[2], al[3]);
    ((float4*)al_d)[node] = make_float4(al[4], al[5], al[6], al[7]);
  } else {  // degree histogram
    int e = (b - 353 - gD) * 256 + tid;
    if (e >= E) return;
    int d = dstv[e];
    atomicAdd(&deg[d], 1);
    atomicAdd(&asum[d], eattr[e]);
  }
}

// Single-pass scan: thread t owns C contiguous nodes.
__global__ __launch_bounds__(1024) void scan_kernel(const int* __restrict__ deg,
                                                    int* __restrict__ row_ptr, int n) {
  int tid = threadIdx.x, wid = tid >> 6, lane = tid & 63;
  int C = (n + 1023) >> 10;
  int base = tid * C;
  int sum = 0;
  for (int j = 0; j < C; j++) {
    int i = base + j;
    if (i < n) sum += deg[i] + 1;
  }
  int sc = sum;
#pragma unroll
  for (int off = 1; off < 64; off <<= 1) {
    int t = __shfl_up(sc, off, 64);
    if (lane >= off) sc += t;
  }
  __shared__ int wtot[16], wexc[16];
  __shared__ int total;
  if (lane == 63) wtot[wid] = sc;
  __syncthreads();
  if (tid == 0) {
    int run = 0;
#pragma unroll
    for (int i = 0; i < 16; i++) { int t = wtot[i]; wexc[i] = run; run += t; }
    total = run;
  }
  __syncthreads();
  int run = wexc[wid] + (sc - sum);
  for (int j = 0; j < C; j++) {
    int i = base + j;
    if (i < n) {
      row_ptr[i] = run;
      run += deg[i] + 1;
    }
  }
  if (tid == 0) row_ptr[n] = total;
}

// Merged CSR fill (+ dstpos): t<E scatters real edges; t>=E appends self loop.
__global__ void fill_kernel(const int* __restrict__ src, const int* __restrict__ dst,
                            const float* __restrict__ eattr, const int* __restrict__ row_ptr,
                            const int* __restrict__ deg, const float* __restrict__ asum,
                            int* __restrict__ fill, int2* __restrict__ edge,
                            int* __restrict__ dstpos, int E, int n) {
  int t = blockIdx.x * 256 + threadIdx.x;
  if (t < E) {
    int d = dst[t];
    int pos = row_ptr[d] + atomicAdd(&fill[d], 1);
    edge[pos] = make_int2(src[t], __float_as_int(eattr[t]));
    dstpos[pos] = d;
  } else {
    int i = t - E;
    if (i < n) {
      int dg = deg[i];
      int pos = row_ptr[i] + dg;
      edge[pos] = make_int2(i, __float_as_int(asum[i] / fmaxf((float)dg, 1.f)));
      dstpos[pos] = i;
    }
  }
}

// Edge-parallel weights, H=4: wrec[p] = {src, h2(w0,w1), h2(w2,w3), 0}.
__global__ void ew4_kernel(const int2* __restrict__ edge, const int* __restrict__ dstpos,
                           const float* __restrict__ al_s, const float* __restrict__ al_d,
                           const float* __restrict__ wedot, int4* __restrict__ wrec, int P) {
  int p = blockIdx.x * 256 + threadIdx.x;
  if (p >= P) return;
  int2 g = edge[p];
  int d = dstpos[p];
  float ev = __int_as_float(g.y);
  float4 as4 = ((const float4*)al_s)[g.x];
  float4 ad4 = ((const float4*)al_d)[d];
  float w[4];
#pragma unroll
  for (int h = 0; h < 4; h++) {
    float a = ((const float*)&as4)[h] + ((const float*)&ad4)[h] + ev * wedot[h];
    a = fmaxf(a, 0.2f * a);
    a = fminf(a, 11.f);
    w[h] = __expf(a);
  }
  __half2 p01 = __floats2half2_rn(w[0], w[1]);
  __half2 p23 = __floats2half2_rn(w[2], w[3]);
  wrec[p] = make_int4(g.x, h2i(p01), h2i(p23), 0);
}

// Edge-parallel weights, H=1: wrec[p] = {src, f32 w}.
__global__ void ew1_kernel(const int2* __restrict__ edge, const int* __restrict__ dstpos,
                           const float* __restrict__ al_s, const float* __restrict__ al_d,
                           const float* __restrict__ wedot, int2* __restrict__ wrec, int P) {
  int p = blockIdx.x * 256 + threadIdx.x;
  if (p >= P) return;
  int2 g = edge[p];
  int d = dstpos[p];
  float a = al_s[g.x] + al_d[d] + __int_as_float(g.y) * wedot[0];
  a = fmaxf(a, 0.2f * a);
  a = fminf(a, 30.f);
  wrec[p] = make_int2(g.x, __float_as_int(__expf(a)));
}

// per-lane fp16 weight extraction from a (scalar) int4 record
__device__ __forceinline__ float w_of_rec(int4 r, int h4) {
  int wdw = (h4 < 2) ? r.y : r.z;
  __half2 hh = i2h(wdw);
  return (h4 & 1) ? __high2float(hh) : __low2float(hh);
}

// Layer-0 fused aggregate-then-project: one wave per node.
// Recs via SCALAR loads (4/step, s_load); row loads: lane=(es,c), one vmem
// instr covers 4 edges' x rows. Reduce over es via shfl_xor(16,32);
// projection 16->256 with W0 fragment in registers; bias+ELU; bf16 out.
__global__ __launch_bounds__(256) void agg0_kernel(
    const int* __restrict__ row_ptr, const int4* __restrict__ wrec,
    const float* __restrict__ x, const float* __restrict__ W0,
    const float* __restrict__ bias, unsigned short* __restrict__ out, int n) {
  int node = blockIdx.x * 4 + (threadIdx.x >> 6);
  if (node >= n) return;
  int lane = threadIdx.x & 63;
  int es = lane >> 4;
  int c = lane & 15;
  int beg = row_ptr[node], end = row_ptr[node + 1];
  int cnt = end - beg;
  float Z[4] = {0.f, 0.f, 0.f, 0.f};
  float den[4] = {0.f, 0.f, 0.f, 0.f};
  for (int i = 0; i < cnt; i += 4) {
    int base = __builtin_amdgcn_readfirstlane(beg + i);
    int4 r0 = wrec[base], r1 = wrec[base + 1], r2 = wrec[base + 2], r3 = wrec[base + 3];
    // lane's rec by es
    int4 rm = (es == 0) ? r0 : (es == 1) ? r1 : (es == 2) ? r2 : r3;
    bool valid = (i + es) < cnt;
    int src = valid ? rm.x : 0;
    float xv = x[(size_t)src * 16 + c];
    __half2 p01 = i2h(rm.y), p23 = i2h(rm.z);
    float w0 = __low2float(p01), w1 = __high2float(p01);
    float w2 = __low2float(p23), w3 = __high2float(p23);
    if (!valid) { w0 = 0.f; w1 = 0.f; w2 = 0.f; w3 = 0.f; }
    den[0] += w0;
    den[1] += w1;
    den[2] += w2;
    den[3] += w3;
    Z[0] = fmaf(w0, xv, Z[0]);
    Z[1] = fmaf(w1, xv, Z[1]);
    Z[2] = fmaf(w2, xv, Z[2]);
    Z[3] = fmaf(w3, xv, Z[3]);
  }
#pragma unroll
  for (int h = 0; h < 4; h++) {
    Z[h] += __shfl_xor(Z[h], 16, 64);
    Z[h] += __shfl_xor(Z[h], 32, 64);
    den[h] += __shfl_xor(den[h], 16, 64);
    den[h] += __shfl_xor(den[h], 32, 64);
  }
  int h = es;
  float zsel = (h == 0) ? Z[0] : (h == 1) ? Z[1] : (h == 2) ? Z[2] : Z[3];
  float dsel = (h == 0) ? den[0] : (h == 1) ? den[1] : (h == 2) ? den[2] : den[3];
  float zn = zsel / (dsel + 1e-16f);
  float4 w0r[16];
#pragma unroll
  for (int cc = 0; cc < 16; cc++) w0r[cc] = ((const float4*)(W0 + (size_t)cc * 256))[lane];
  float zc[16];
  int basel = lane & 48;
#pragma unroll
  for (int cc = 0; cc < 16; cc++) zc[cc] = __shfl(zn, basel + cc, 64);
  float o[4];
  float4 b4 = ((const float4*)bias)[lane];
#pragma unroll
  for (int jj = 0; jj < 4; jj++) o[jj] = ((const float*)&b4)[jj];
#pragma unroll
  for (int cc = 0; cc < 16; cc++) {
#pragma unroll
    for (int jj = 0; jj < 4; jj++) o[jj] = fmaf(zc[cc], ((const float*)&w0r[cc])[jj], o[jj]);
  }
  ushort4 o4;
  float ox = o[0] > 0.f ? o[0] : expm1f(o[0]);
  float oy = o[1] > 0.f ? o[1] : expm1f(o[1]);
  float oz = o[2] > 0.f ? o[2] : expm1f(o[2]);
  float ow = o[3] > 0.f ? o[3] : expm1f(o[3]);
  o4.x = f2bf(ox);
  o4.y = f2bf(oy);
  o4.z = f2bf(oz);
  o4.w = f2bf(ow);
  ((ushort4*)out)[(size_t)node * 64 + lane] = o4;
}

// bf16 MFMA GEMM (K=256): bf16 out; al_s/al_d from the extra va col-tile.
template <int M, int H>
__global__ __launch_bounds__(64) void mfma_gemm_dots(
    const unsigned short* __restrict__ Abf, const unsigned short* __restrict__ Wfrag,
    unsigned short* __restrict__ out, float* __restrict__ al_s, float* __restrict__ al_d,
    int n) {
  int lane = threadIdx.x;
  int row0 = blockIdx.x * 16;
  int m = lane & 15, q = lane >> 4;

  short8 afrag[8];
  int r = row0 + m;
  if (r < n) {
    const short8* arow = (const short8*)(Abf + (size_t)r * 256);
#pragma unroll
    for (int ks = 0; ks < 8; ks++) afrag[ks] = arow[ks * 4 + q];
  } else {
#pragma unroll
    for (int ks = 0; ks < 8; ks++) afrag[ks] = (short8)0;
  }

  const short8* wf = (const short8*)Wfrag;

  auto epi = [&](int tile, float4v acc) {
    int col = tile * 16 + m;
#pragma unroll
    for (int reg = 0; reg < 4; reg++) {
      int rr = row0 + q * 4 + reg;
      if (rr < n) out[(size_t)rr * M + col] = f2bf(acc[reg]);
    }
  };

  for (int nt = 0; nt < M / 16; nt += 2) {
    const short8* b0 = wf + (size_t)nt * 8 * 64 + lane;
    const short8* b1 = b0 + 8 * 64;
    short8 bf0[8], bf1[8];
#pragma unroll
    for (int ks = 0; ks < 8; ks++) {
      bf0[ks] = b0[ks * 64];
      bf1[ks] = b1[ks * 64];
    }
    float4v acc0 = {0.f, 0.f, 0.f, 0.f};
    float4v acc1 = {0.f, 0.f, 0.f, 0.f};
#pragma unroll
    for (int ks = 0; ks < 8; ks++) {
      acc0 = __builtin_amdgcn_mfma_f32_16x16x32_bf16(afrag[ks], bf0[ks], acc0, 0, 0, 0);
      acc1 = __builtin_amdgcn_mfma_f32_16x16x32_bf16(afrag[ks], bf1[ks], acc1, 0, 0, 0);
    }
    epi(nt, acc0);
    epi(nt + 1, acc1);
  }

  {
    const short8* bl = wf + (size_t)(M / 16) * 8 * 64 + lane;
    short8 bf[8];
#pragma unroll
    for (int ks = 0; ks < 8; ks++) bf[ks] = bl[ks * 64];
    float4v acc = {0.f, 0.f, 0.f, 0.f};
#pragma unroll
    for (int ks = 0; ks < 8; ks++)
      acc = __builtin_amdgcn_mfma_f32_16x16x32_bf16(afrag[ks], bf[ks], acc, 0, 0, 0);
#pragma unroll
    for (int reg = 0; reg < 4; reg++) {
      int rr = row0 + q * 4 + reg;
      if (rr < n) {
        if (m < H) al_s[(size_t)rr * H + m] = acc[reg];
        else if (m < 2 * H) al_d[(size_t)rr * H + (m - H)] = acc[reg];
      }
    }
  }
}

// H=4 aggregation: one wave per node; recs via SCALAR loads (4/step);
// rows: halves process interleaved edges (half0: e0,e2 ; half1: e1,e3),
// one vmem instr = two 512B rows. Merge via shfl_xor(32). bias+ELU; bf16 out.
__global__ __launch_bounds__(256) void agg4_kernel(
    const int* __restrict__ row_ptr, const int4* __restrict__ wrec,
    const unsigned short* __restrict__ B, const float* __restrict__ bias,
    unsigned short* __restrict__ out, int n) {
  int node = blockIdx.x * 4 + (threadIdx.x >> 6);
  if (node >= n) return;
  int lane = threadIdx.x & 63;
  int half = lane >> 5;
  int l = lane & 31;
  int h4 = l >> 3;
  int beg = row_ptr[node], end = row_ptr[node + 1];
  int cnt = end - beg;

  float acc[8];
#pragma unroll
  for (int j = 0; j < 8; j++) acc[j] = 0.f;
  float den = 0.f;

  for (int i = 0; i < cnt; i += 4) {
    int base = __builtin_amdgcn_readfirstlane(beg + i);
    int4 r0 = wrec[base], r1 = wrec[base + 1], r2 = wrec[base + 2], r3 = wrec[base + 3];
    bool v0 = i < cnt, v1 = i + 1 < cnt, v2 = i + 2 < cnt, v3 = i + 3 < cnt;
    // lane's two edges: A = half? e1 : e0 ; B = half? e3 : e2
    bool vA = half ? v1 : v0;
    bool vB = half ? v3 : v2;
    int srcA = half ? r1.x : r0.x;
    int srcB = half ? r3.x : r2.x;
    srcA = vA ? srcA : 0;
    srcB = vB ? srcB : 0;
    short8 rowA = ((const short8*)(B + (size_t)srcA * 256))[l];
    short8 rowB = ((const short8*)(B + (size_t)srcB * 256))[l];
    float wA = half ? w_of_rec(r1, h4) : w_of_rec(r0, h4);
    float wB = half ? w_of_rec(r3, h4) : w_of_rec(r2, h4);
    wA = vA ? wA : 0.f;
    wB = vB ? wB : 0.f;
    den += wA + wB;
    const unsigned short* pa = (const unsigned short*)&rowA;
    const unsigned short* pb = (const unsigned short*)&rowB;
#pragma unroll
    for (int j = 0; j < 8; j++) acc[j] = fmaf(wA, bf2f(pa[j]), acc[j]);
#pragma unroll
    for (int j = 0; j < 8; j++) acc[j] = fmaf(wB, bf2f(pb[j]), acc[j]);
  }

  den += __shfl_xor(den, 32, 64);
#pragma unroll
  for (int j = 0; j < 8; j++) acc[j] += __shfl_xor(acc[j], 32, 64);

  if (half == 0) {
    float inv = 1.f / (den + 1e-16f);
    float4 b0 = ((const float4*)bias)[l * 2];
    float4 b1 = ((const float4*)bias)[l * 2 + 1];
    unsigned short o8[8];
#pragma unroll
    for (int j = 0; j < 8; j++) {
      float bjv = (j < 4) ? ((const float*)&b0)[j] : ((const float*)&b1)[j - 4];
      float o = acc[j] * inv + bjv;
      o = o > 0.f ? o : expm1f(o);
      o8[j] = f2bf(o);
    }
    ((short8*)(out + (size_t)node * 256))[l] = *(short8*)o8;
  }
}

// H=1 aggregation + bias + LayerNorm: one wave per node; recs via SCALAR
// loads (4/step); rows: quad q takes edge q (one vmem instr = four 128B rows).
__global__ __launch_bounds__(256) void agg_ln_kernel(
    const int* __restrict__ row_ptr, const int2* __restrict__ wrec,
    const unsigned short* __restrict__ B, const float* __restrict__ bias,
    const float* __restrict__ ln_g, const float* __restrict__ ln_b,
    float* __restrict__ out, int n) {
  int node = blockIdx.x * 4 + (threadIdx.x >> 6);
  if (node >= n) return;
  int lane = threadIdx.x & 63;
  int q = lane >> 4;
  int l = lane & 15;
  int beg = row_ptr[node], end = row_ptr[node + 1];
  int cnt = end - beg;

  float4 acc = make_float4(0.f, 0.f, 0.f, 0.f);
  float den = 0.f;

  for (int i = 0; i < cnt; i += 4) {
    int base = __builtin_amdgcn_readfirstlane(beg + i);
    int2 r0 = wrec[base], r1 = wrec[base + 1], r2 = wrec[base + 2], r3 = wrec[base + 3];
    int2 rm = (q == 0) ? r0 : (q == 1) ? r1 : (q == 2) ? r2 : r3;
    bool valid = (i + q) < cnt;
    int src = valid ? rm.x : 0;
    float w = valid ? __int_as_float(rm.y) : 0.f;
    ushort4 bv = ((const ushort4*)(B + (size_t)src * 64))[l];
    den += w;
    acc.x = fmaf(w, bf2f(bv.x), acc.x);
    acc.y = fmaf(w, bf2f(bv.y), acc.y);
    acc.z = fmaf(w, bf2f(bv.z), acc.z);
    acc.w = fmaf(w, bf2f(bv.w), acc.w);
  }

  den += __shfl_xor(den, 32, 64);
  den += __shfl_xor(den, 16, 64);
  acc.x += __shfl_xor(acc.x, 32, 64);
  acc.y += __shfl_xor(acc.y, 32, 64);
  acc.z += __shfl_xor(acc.z, 32, 64);
  acc.w += __shfl_xor(acc.w, 32, 64);
  acc.x += __shfl_xor(acc.x, 16, 64);
  acc.y += __shfl_xor(acc.y, 16, 64);
  acc.z += __shfl_xor(acc.z, 16, 64);
  acc.w += __shfl_xor(acc.w, 16, 64);

  float inv = 1.f / (den + 1e-16f);
  float4 b4 = ((const float4*)bias)[l];
  float4 o;
  o.x = acc.x * inv + b4.x;
  o.y = acc.y * inv + b4.y;
  o.z = acc.z * inv + b4.z;
  o.w = acc.w * inv + b4.w;
  float s = (o.x + o.y) + (o.z + o.w);
#pragma unroll
  for (int off = 1; off < 16; off <<= 1) s += __shfl_xor(s, off, 64);
  float mu = s * (1.f / 64.f);
  float dx = o.x - mu, dy = o.y - mu, dz = o.z - mu, dw = o.w - mu;
  float v = (dx * dx + dy * dy) + (dz * dz + dw * dw);
#pragma unroll
  for (int off = 1; off < 16; off <<= 1) v += __shfl_xor(v, off, 64);
  float rs = rsqrtf(v * (1.f / 64.f) + 1e-5f);
  if (q == 0) {
    float4 g4 = ((const float4*)ln_g)[l];
    float4 lb4 = ((const float4*)ln_b)[l];
    float4 rr;
    rr.x = dx * rs * g4.x + lb4.x;
    rr.y = dy * rs * g4.y + lb4.y;
    rr.z = dz * rs * g4.z + lb4.z;
    rr.w = dw * rs * g4.w + lb4.w;
    ((float4*)(out + (size_t)node * 64))[l] = rr;
  }
}

extern "C" void kernel_launch(void* const* d_in, const int* in_sizes, int n_in,
                              void* d_out, int out_size, void* d_ws, size_t ws_size,
                              hipStream_t stream) {
  const float* x = (const float*)d_in[0];
  const int* ei = (const int*)d_in[1];
  const float* eattr = (const float*)d_in[2];
  const float* W0 = (const float*)d_in[3];
  const float* as0 = (const float*)d_in[4];
  const float* ad0 = (const float*)d_in[5];
  const float* We0 = (const float*)d_in[6];
  const float* ae0 = (const float*)d_in[7];
  const float* b0 = (const float*)d_in[8];
  const float* W1 = (const float*)d_in[9];
  const float* as1 = (const float*)d_in[10];
  const float* ad1 = (const float*)d_in[11];
  const float* We1 = (const float*)d_in[12];
  const float* ae1 = (const float*)d_in[13];
  const float* b1 = (const float*)d_in[14];
  const float* W2 = (const float*)d_in[15];
  const float* as2 = (const float*)d_in[16];
  const float* ad2 = (const float*)d_in[17];
  const float* We2 = (const float*)d_in[18];
  const float* ae2 = (const float*)d_in[19];
  const float* b2 = (const float*)d_in[20];
  const float* lng = (const float*)d_in[21];
  const float* lnb = (const float*)d_in[22];
  float* outp = (float*)d_out;

  const int N = in_sizes[0] / 16;
  const int E = in_sizes[1] / 2;
  const int P = E + N;
  const int* srcv = ei;
  const int* dstv = ei + E;

  char* w = (char*)d_ws;
  size_t off = 0;
  auto alloc = [&](size_t bytes) -> void* {
    void* p = w + off;
    off += (bytes + 255) & ~(size_t)255;
    return p;
  };
  int* deg = (int*)alloc((size_t)N * 4);
  float* asum = (float*)alloc((size_t)N * 4);
  int* fill = (int*)alloc((size_t)N * 4);
  size_t zero_bytes = off;
  int* row_ptr = (int*)alloc((size_t)(N + 1) * 4);
  int2* edge = (int2*)alloc((size_t)P * 8);
  int* dstpos = (int*)alloc((size_t)P * 4);
  int4* wrec4 = (int4*)alloc((size_t)(P + 8) * 16);  // +8: scalar-load overread pad
  int2* wrec1 = (int2*)wrec4;                        // alias (sequential use)
  float* wedot = (float*)alloc(16 * 4);
  float* al_s = (float*)alloc((size_t)N * 4 * 4);
  float* al_d = (float*)alloc((size_t)N * 4 * 4);
  unsigned short* Wf1 = (unsigned short*)alloc((size_t)17 * 4096 * 2);
  unsigned short* Wf2 = (unsigned short*)alloc((size_t)5 * 4096 * 2);
  unsigned short* bufA = (unsigned short*)alloc((size_t)N * 256 * 2);
  unsigned short* bufB = (unsigned short*)alloc((size_t)N * 256 * 2);
  (void)ws_size;

  hipMemsetAsync(d_ws, 0, zero_bytes, stream);

  int gE = (E + 255) / 256;
  int gP = (P + 255) / 256;
  int gD = (N + 255) / 256;

  k1_kernel<<<353 + gD + gE, 256, 0, stream>>>(
      x, dstv, eattr, W0, as0, ad0, We0, ae0, W1, as1, ad1, We1, ae1,
      W2, as2, ad2, We2, ae2, Wf1, Wf2, wedot, al_s, al_d, deg, asum, N, E, gD);
  scan_kernel<<<1, 1024, 0, stream>>>(deg, row_ptr, N);
  fill_kernel<<<gP, 256, 0, stream>>>(srcv, dstv, eattr, row_ptr, deg, asum, fill,
                                      edge, dstpos, E, N);

  int gStrip = (N + 15) / 16;
  int gNode4 = (N + 3) / 4;

  // ---- layer 0: edge weights, then aggregate x + project (fused)
  ew4_kernel<<<gP, 256, 0, stream>>>(edge, dstpos, al_s, al_d, wedot, wrec4, P);
  agg0_kernel<<<gNode4, 256, 0, stream>>>(row_ptr, wrec4, x, W0, b0, bufA, N);

  // ---- layer 1
  mfma_gemm_dots<256, 4><<<gStrip, 64, 0, stream>>>(bufA, Wf1, bufB, al_s, al_d, N);
  ew4_kernel<<<gP, 256, 0, stream>>>(edge, dstpos, al_s, al_d, wedot + 4, wrec4, P);
  agg4_kernel<<<gNode4, 256, 0, stream>>>(row_ptr, wrec4, bufB, b1, bufA, N);

  // ---- layer 2 (+ LayerNorm -> d_out)
  mfma_gemm_dots<64, 1><<<gStrip, 64, 0, stream>>>(bufA, Wf2, bufB, al_s, al_d, N);
  ew1_kernel<<<gP, 256, 0, stream>>>(edge, dstpos, al_s, al_d, wedot + 8, wrec1, P);
  agg_ln_kernel<<<gNode4, 256, 0, stream>>>(row_ptr, wrec1, bufB, b2, lng, lnb, outp, N);
}